// Round 3
// baseline (428914.453 us; speedup 1.0000x reference)
//
#include <hip/hip_runtime.h>

#define NBLK 256
#define NTHR 512

// ---------------- ws float offsets (no aliasing anywhere) ----------------
#define OFF_PRE   0u            // [400][32][256]
#define OFF_PMT   3276800u      // [32][128][400]
#define OFF_PMTMP 4915200u      // [32][400][128]
#define OFF_GATT  6553600u      // [8][32][4096]
#define OFF_GDEC  7602176u      // [8][32][4096]
#define OFF_E     8650752u      // [32][400]
#define OFF_Q     8663552u      // [32][128]
#define OFF_AH    8667648u
#define OFF_AC    8700416u
#define OFF_DH    8733184u
#define OFF_DC    8765952u
#define OFF_AW    8798720u
#define OFF_AWC   8811520u
#define OFF_CTX   8824320u
#define OFF_BAR   8840704u      // barrier counters (unsigned)
#define WS_TOTAL  8840768u      // 35.4 MB (<37.7MB proven available)

__device__ __forceinline__ float sigm(float x){ return 1.f/(1.f+__expf(-x)); }
__device__ __forceinline__ float ftanh(float x){
  x = fminf(fmaxf(x,-15.f),15.f);
  float e = __expf(2.f*x);
  return (e-1.f)/(e+1.f);
}

// device-scope grid barrier; bar[0]=count, bar[1]=generation (zeroed each call)
__device__ __forceinline__ void gsync(unsigned* bar){
  __syncthreads();
  if (threadIdx.x==0){
    __threadfence();
    unsigned g = __hip_atomic_load(bar+1, __ATOMIC_ACQUIRE, __HIP_MEMORY_SCOPE_AGENT);
    unsigned arrived = __hip_atomic_fetch_add(bar, 1u, __ATOMIC_ACQ_REL, __HIP_MEMORY_SCOPE_AGENT);
    if (arrived == NBLK-1u){
      __hip_atomic_store(bar, 0u, __ATOMIC_RELAXED, __HIP_MEMORY_SCOPE_AGENT);
      __hip_atomic_fetch_add(bar+1, 1u, __ATOMIC_ACQ_REL, __HIP_MEMORY_SCOPE_AGENT);
    } else {
      while (__hip_atomic_load(bar+1, __ATOMIC_ACQUIRE, __HIP_MEMORY_SCOPE_AGENT) == g){
        __builtin_amdgcn_s_sleep(8);
      }
    }
  }
  __syncthreads();
}

// -------------------- precompute --------------------

__global__ void zero_kernel(float* p, unsigned n){
  unsigned i = blockIdx.x*256u + threadIdx.x;
  if (i<n) p[i]=0.f;
}

// pre[t*32+b][j] = relu(relu(dec_in @ W1) @ W2)
__global__ __launch_bounds__(256) void prenet_kernel(const float* __restrict__ mel_target,
    const float* __restrict__ W1, const float* __restrict__ W2, float* __restrict__ pre)
{
  __shared__ float din[80];
  __shared__ float h1[256];
  int blk = blockIdx.x;          // t*32 + b
  int t = blk >> 5, b = blk & 31;
  int tid = threadIdx.x;
  if (tid < 80) din[tid] = (t==0) ? 0.f : mel_target[b*32000 + tid*400 + (t-1)];
  __syncthreads();
  float s=0.f;
  for (int c=0;c<80;c++) s += din[c]*W1[c*256+tid];
  h1[tid] = fmaxf(s,0.f);
  __syncthreads();
  float s2=0.f;
  for (int c=0;c<256;c++) s2 += h1[c]*W2[c*256+tid];
  pre[(size_t)blk*256 + tid] = fmaxf(s2,0.f);
}

// pm_tmp[b*400+t][a] = sum_d memory[b][t][d]*memory_W[d][a]
__global__ __launch_bounds__(128) void pm_kernel(const float* __restrict__ memory,
    const float* __restrict__ memory_W, float* __restrict__ pm)
{
  __shared__ float mrow[512];
  int blk = blockIdx.x;  // b*400+t
  int tid = threadIdx.x;
  const float* src = memory + (size_t)blk*512;
  for (int i=tid;i<512;i+=128) mrow[i]=src[i];
  __syncthreads();
  float s=0.f;
  for (int d=0; d<512; d++) s += mrow[d]*memory_W[d*128+tid];
  pm[(size_t)blk*128+tid]=s;
}

// pmT[b][a][t] = pm_tmp[b][t][a]
__global__ __launch_bounds__(256) void pmt_kernel(const float* __restrict__ pm,
    float* __restrict__ pmT)
{
  __shared__ float s[64][129];
  int b = blockIdx.x, t0 = blockIdx.y*64, tid = threadIdx.x;
  for (int i=tid; i<64*128; i+=256){
    int t = i>>7, a = i&127;
    int tg = t0+t;
    s[t][a] = (tg<400) ? pm[(size_t)b*51200 + tg*128 + a] : 0.f;
  }
  __syncthreads();
  for (int i=tid; i<64*128; i+=256){
    int a = i>>6, t = i&63;
    int tg = t0+t;
    if (tg<400) pmT[(size_t)b*51200 + a*400 + tg] = s[t][a];
  }
}

// -------------------- the cooperative 400-step loop --------------------

__global__ void __launch_bounds__(NTHR) decoder_loop(
    const float* __restrict__ memory, const int* __restrict__ mlen,
    const float* __restrict__ query_W, const float* __restrict__ wc,
    const float* __restrict__ wd, const float* __restrict__ vvec,
    const float* __restrict__ att_Wih, const float* __restrict__ att_Whh, const float* __restrict__ att_b,
    const float* __restrict__ dec_Wih, const float* __restrict__ dec_Whh, const float* __restrict__ dec_b,
    const float* __restrict__ proj_W, const float* __restrict__ proj_b,
    const float* __restrict__ gate_W, const float* __restrict__ gate_b,
    float* __restrict__ ws, float* __restrict__ out)
{
  __shared__ float sm[10400];    // 41.6 KB, phase-unioned
  const int bid = blockIdx.x, tid = threadIdx.x;
  float* PRE = ws + OFF_PRE;
  float* PMT = ws + OFF_PMT;
  float* GATT = ws + OFF_GATT;
  float* GDEC = ws + OFF_GDEC;
  float* E  = ws + OFF_E;
  float* Q  = ws + OFF_Q;
  float* AH = ws + OFF_AH;
  float* AC = ws + OFF_AC;
  float* DH = ws + OFF_DH;
  float* DC = ws + OFF_DC;
  float* AW = ws + OFF_AW;
  float* AWC = ws + OFF_AWC;
  float* CTX = ws + OFF_CTX;
  unsigned* bar = (unsigned*)(ws + OFF_BAR);
  float* aligns = out + 1036800;

  const int xA = bid & 31, yA = bid >> 5;   // gates: colblock(128), K-slice
  const int rg = tid >> 6, cg = tid & 63;
  const int bC = bid / 7, ytC = bid - bC*7; // energies (bid<224)
  const int bD = bid >> 3, yD = bid & 7;    // softmax+ctx

  for (int t=0; t<400; t++){
    // ---------- Phase A: attention-LSTM gates (all 256 blocks) ----------
    {
      __syncthreads();   // guard sm vs Phase F of previous iteration (same block)
      const float* pre_t = PRE + (size_t)t*8192;
      const int k_beg = yA*224;
      for (int idx=tid; idx<32*224; idx+=NTHR){
        int r = idx/224, kk = idx - r*224;
        int k = k_beg + kk;
        float v;
        if (k<256) v = pre_t[r*256+k];
        else if (k<768) v = CTX[r*512 + (k-256)];
        else v = AH[r*1024 + (k-768)];
        sm[r*224+kk] = v;
      }
      __syncthreads();
      const int colb = xA*128 + cg*2;
      float a0x=0,a0y=0,a1x=0,a1y=0,a2x=0,a2y=0,a3x=0,a3y=0;
      const float* x0 = sm + (rg*4+0)*224;
      const float* x1 = sm + (rg*4+1)*224;
      const float* x2 = sm + (rg*4+2)*224;
      const float* x3 = sm + (rg*4+3)*224;
      #pragma unroll 4
      for (int kk=0; kk<224; kk++){
        int k = k_beg + kk;
        const float* wrow = (k<768) ? (att_Wih + (size_t)k*4096) : (att_Whh + (size_t)(k-768)*4096);
        float2 w = *(const float2*)(wrow + colb);
        float v0=x0[kk], v1=x1[kk], v2=x2[kk], v3=x3[kk];
        a0x+=v0*w.x; a0y+=v0*w.y; a1x+=v1*w.x; a1y+=v1*w.y;
        a2x+=v2*w.x; a2y+=v2*w.y; a3x+=v3*w.x; a3y+=v3*w.y;
      }
      float* gp = GATT + (size_t)yA*131072 + colb;
      *(float2*)(gp + (size_t)(rg*4+0)*4096) = make_float2(a0x,a0y);
      *(float2*)(gp + (size_t)(rg*4+1)*4096) = make_float2(a1x,a1y);
      *(float2*)(gp + (size_t)(rg*4+2)*4096) = make_float2(a2x,a2y);
      *(float2*)(gp + (size_t)(rg*4+3)*4096) = make_float2(a3x,a3y);
    }
    gsync(bar);

    // ---------- Phase B: att pointwise + q (32 blocks) ----------
    if (bid < 32){
      const int b = bid;
      float* ah_s = sm; float* qp = sm+1024;
      for (int u=0; u<2; u++){
        int j = tid + u*NTHR;
        float gi=att_b[j], gf=att_b[1024+j], gg=att_b[2048+j], go=att_b[3072+j];
        for (int s=0; s<8; s++){
          const float* g = GATT + (size_t)s*131072 + (size_t)b*4096;
          gi+=g[j]; gf+=g[1024+j]; gg+=g[2048+j]; go+=g[3072+j];
        }
        float c = sigm(gf)*AC[b*1024+j] + sigm(gi)*ftanh(gg);
        float h = sigm(go)*ftanh(c);
        AC[b*1024+j]=c; AH[b*1024+j]=h; ah_s[j]=h;
      }
      __syncthreads();
      { int a = tid & 127, sl = tid >> 7;
        float s=0.f; int kb = sl*256;
        for (int k=kb;k<kb+256;k++) s += ah_s[k]*query_W[k*128+a];
        qp[sl*128+a]=s; }
      __syncthreads();
      if (tid<128) Q[bid*128+tid] = qp[tid]+qp[128+tid]+qp[256+tid]+qp[384+tid];
    }
    gsync(bar);

    // ---------- Phase C: energies (224 blocks: 32 b x 7 t-chunks) ----------
    if (bid < 224){
      const int b = bC, t0 = ytC*64;
      float* aw_s = sm;        float* awc_s = sm+400;
      float* loc  = sm+800;    float* wd_s  = sm+2912;
      float* wc_s = sm+7008;   float* q_s   = sm+8992;
      float* v_s  = sm+9120;   float* ep    = sm+9248;
      for (int i=tid;i<400;i+=NTHR){ aw_s[i]=AW[b*400+i]; awc_s[i]=AWC[b*400+i]; }
      for (int i=tid;i<4096;i+=NTHR) wd_s[i]=wd[i];
      for (int i=tid;i<1984;i+=NTHR) wc_s[i]=wc[i];
      if (tid<128){ q_s[tid]=Q[b*128+tid]; v_s[tid]=vvec[tid]; }
      __syncthreads();
      { int tt = tid & 63, fs = tid >> 6;
        float cf0=0,cf1=0,cf2=0,cf3=0;
        int f0 = fs*4;
        for (int k=0;k<31;k++){
          int gi2 = t0 + tt + k - 15;
          float a1 = (gi2>=0 && gi2<400) ? aw_s[gi2] : 0.f;
          float a2 = (gi2>=0 && gi2<400) ? awc_s[gi2] : 0.f;
          cf0 += wc_s[(f0+0)*62+k]*a1 + wc_s[(f0+0)*62+31+k]*a2;
          cf1 += wc_s[(f0+1)*62+k]*a1 + wc_s[(f0+1)*62+31+k]*a2;
          cf2 += wc_s[(f0+2)*62+k]*a1 + wc_s[(f0+2)*62+31+k]*a2;
          cf3 += wc_s[(f0+3)*62+k]*a1 + wc_s[(f0+3)*62+31+k]*a2;
        }
        loc[tt*33+f0+0]=cf0; loc[tt*33+f0+1]=cf1;
        loc[tt*33+f0+2]=cf2; loc[tt*33+f0+3]=cf3;
      }
      __syncthreads();
      { int tt = tid & 63, as = tid >> 6;
        int tg = t0 + tt; bool act = (tg<400);
        float e = 0.f;
        const float* lrow = loc + tt*33;
        for (int aa=0; aa<16; aa++){
          int a = as*16+aa;
          float pmv = act ? PMT[(size_t)b*51200 + a*400 + tg] : 0.f;
          float lv = 0.f;
          #pragma unroll
          for (int f=0; f<32; f++) lv += lrow[f]*wd_s[f*128+a];
          e += ftanh(q_s[a]+pmv+lv)*v_s[a];
        }
        ep[as*64+tt] = e;
      }
      __syncthreads();
      if (tid < 64){
        int tg = t0 + tid;
        if (tg < 400){
          float ee = 0.f;
          for (int as2=0; as2<8; as2++) ee += ep[as2*64+tid];
          E[b*400+tg] = (tg < mlen[b]) ? ee : -1e30f;
        }
      }
    }
    gsync(bar);

    // ---------- Phase D: softmax + ctx (256 blocks: 32 b x 8 d-chunks) ----------
    {
      const int b = bD, d0 = yD*64;
      float* e_s = sm; float* red = sm+400; float* cp = sm+416;
      float ev = (tid<400) ? E[b*400+tid] : -1e30f;
      float m = ev;
      for (int off=32; off>0; off>>=1) m = fmaxf(m, __shfl_down(m, off, 64));
      if ((tid&63)==0) red[tid>>6]=m;
      __syncthreads();
      if (tid==0){ float mm=red[0]; for (int i=1;i<8;i++) mm=fmaxf(mm,red[i]); red[8]=mm; }
      __syncthreads();
      m = red[8];
      float ex = (tid<400) ? __expf(ev-m) : 0.f;
      float ss = ex;
      for (int off=32; off>0; off>>=1) ss += __shfl_down(ss, off, 64);
      if ((tid&63)==0) red[tid>>6]=ss;
      __syncthreads();
      if (tid==0){ float s2=0.f; for (int i=0;i<8;i++) s2+=red[i]; red[9]=1.f/s2; }
      __syncthreads();
      float anew = ex * red[9];
      if (tid<400) e_s[tid]=anew;
      if (yD==0 && tid<400){
        AW[b*400+tid]=anew;
        AWC[b*400+tid]+=anew;
        aligns[(size_t)b*160000 + t*400 + tid]=anew;
      }
      __syncthreads();
      { int d = tid&63, ts = tid>>6;
        const float* mrow = memory + (size_t)b*204800 + d0 + d;
        float p=0.f;
        for (int tt=ts*50; tt<ts*50+50; tt++) p += e_s[tt]*mrow[tt*512];
        cp[ts*64+d]=p; }
      __syncthreads();
      if (tid<64){
        float s2=0.f;
        for (int ts2=0; ts2<8; ts2++) s2+=cp[ts2*64+tid];
        CTX[b*512+d0+tid]=s2;
      }
    }
    gsync(bar);

    // ---------- Phase E: decoder-LSTM gates (all 256 blocks) ----------
    {
      const int k_beg = yA*320;
      for (int idx=tid; idx<32*320; idx+=NTHR){
        int r = idx/320, kk = idx - r*320;
        int k = k_beg + kk;
        float v;
        if (k<1024) v = AH[r*1024+k];
        else if (k<1536) v = CTX[r*512+(k-1024)];
        else v = DH[r*1024+(k-1536)];
        sm[r*320+kk]=v;
      }
      __syncthreads();
      const int colb = xA*128 + cg*2;
      float a0x=0,a0y=0,a1x=0,a1y=0,a2x=0,a2y=0,a3x=0,a3y=0;
      const float* x0 = sm + (rg*4+0)*320;
      const float* x1 = sm + (rg*4+1)*320;
      const float* x2 = sm + (rg*4+2)*320;
      const float* x3 = sm + (rg*4+3)*320;
      #pragma unroll 4
      for (int kk=0; kk<320; kk++){
        int k = k_beg + kk;
        const float* wrow = (k<1536) ? (dec_Wih + (size_t)k*4096) : (dec_Whh + (size_t)(k-1536)*4096);
        float2 w = *(const float2*)(wrow + colb);
        float v0=x0[kk], v1=x1[kk], v2=x2[kk], v3=x3[kk];
        a0x+=v0*w.x; a0y+=v0*w.y; a1x+=v1*w.x; a1y+=v1*w.y;
        a2x+=v2*w.x; a2y+=v2*w.y; a3x+=v3*w.x; a3y+=v3*w.y;
      }
      float* gp = GDEC + (size_t)yA*131072 + colb;
      *(float2*)(gp + (size_t)(rg*4+0)*4096) = make_float2(a0x,a0y);
      *(float2*)(gp + (size_t)(rg*4+1)*4096) = make_float2(a1x,a1y);
      *(float2*)(gp + (size_t)(rg*4+2)*4096) = make_float2(a2x,a2y);
      *(float2*)(gp + (size_t)(rg*4+3)*4096) = make_float2(a3x,a3y);
    }
    gsync(bar);

    // ---------- Phase F: dec pointwise + projections (32 blocks; no trailing sync) ----------
    if (bid < 32){
      const int b = bid;
      float* do_s = sm; float* pp = sm+1536;
      for (int u=0;u<2;u++){
        int j = tid + u*NTHR;
        float gi=dec_b[j], gf=dec_b[1024+j], gg=dec_b[2048+j], go=dec_b[3072+j];
        for (int s=0;s<8;s++){
          const float* g = GDEC + (size_t)s*131072 + (size_t)b*4096;
          gi+=g[j]; gf+=g[1024+j]; gg+=g[2048+j]; go+=g[3072+j];
        }
        float c = sigm(gf)*DC[b*1024+j] + sigm(gi)*ftanh(gg);
        float h = sigm(go)*ftanh(c);
        DC[b*1024+j]=c; DH[b*1024+j]=h; do_s[j]=h;
      }
      do_s[1024+tid] = CTX[b*512+tid];
      __syncthreads();
      int sl = tid/81, o = tid - sl*81;
      if (sl<6){
        float s=0.f; int kb = sl*256;
        for (int k=kb;k<kb+256;k++){
          float w2 = (o<80) ? proj_W[k*80+o] : gate_W[k];
          s += do_s[k]*w2;
        }
        pp[sl*81+o]=s;
      }
      __syncthreads();
      if (tid<81){
        float r=0.f;
        for (int sl2=0; sl2<6; sl2++) r += pp[sl2*81+tid];
        if (tid<80) out[(size_t)b*32000 + tid*400 + t] = r + proj_b[tid];
        else        out[1024000 + b*400 + t] = r + gate_b[0];
      }
    }
    // F(t) writes only DH/DC/out; next Phase A touches none of them -> no gsync needed
  }
}

// -------------------- launch --------------------

extern "C" void kernel_launch(void* const* d_in, const int* in_sizes, int n_in,
                              void* d_out, int out_size, void* d_ws, size_t ws_size,
                              hipStream_t stream) {
  const float* memory      = (const float*)d_in[0];
  const float* mel_target  = (const float*)d_in[1];
  const int*   mlen        = (const int*)  d_in[2];
  const float* prenet_W1   = (const float*)d_in[3];
  const float* prenet_W2   = (const float*)d_in[4];
  const float* query_W     = (const float*)d_in[5];
  const float* memory_W    = (const float*)d_in[6];
  const float* weight_vec  = (const float*)d_in[7];
  const float* loc_conv_W  = (const float*)d_in[8];
  const float* loc_dense_W = (const float*)d_in[9];
  const float* att_Wih     = (const float*)d_in[10];
  const float* att_Whh     = (const float*)d_in[11];
  const float* att_b       = (const float*)d_in[12];
  const float* dec_Wih     = (const float*)d_in[13];
  const float* dec_Whh     = (const float*)d_in[14];
  const float* dec_b       = (const float*)d_in[15];
  const float* proj_W      = (const float*)d_in[16];
  const float* proj_b      = (const float*)d_in[17];
  const float* gate_W      = (const float*)d_in[18];
  const float* gate_b      = (const float*)d_in[19];
  float* out = (float*)d_out;
  float* ws  = (float*)d_ws;

  float* PRE   = ws + OFF_PRE;
  float* PMT   = ws + OFF_PMT;
  float* PMTMP = ws + OFF_PMTMP;

  // zero ALL used ws every call -> replays bitwise-identical to first call
  hipLaunchKernelGGL(zero_kernel, dim3((WS_TOTAL+255u)/256u), dim3(256), 0, stream, ws, WS_TOTAL);
  hipLaunchKernelGGL(prenet_kernel, dim3(12800), dim3(256), 0, stream,
                     mel_target, prenet_W1, prenet_W2, PRE);
  hipLaunchKernelGGL(pm_kernel, dim3(12800), dim3(128), 0, stream, memory, memory_W, PMTMP);
  hipLaunchKernelGGL(pmt_kernel, dim3(32,7), dim3(256), 0, stream, PMTMP, PMT);

  void* args[] = {
    (void*)&memory, (void*)&mlen, (void*)&query_W, (void*)&loc_conv_W,
    (void*)&loc_dense_W, (void*)&weight_vec,
    (void*)&att_Wih, (void*)&att_Whh, (void*)&att_b,
    (void*)&dec_Wih, (void*)&dec_Whh, (void*)&dec_b,
    (void*)&proj_W, (void*)&proj_b, (void*)&gate_W, (void*)&gate_b,
    (void*)&ws, (void*)&out
  };
  hipLaunchCooperativeKernel((const void*)decoder_loop, dim3(NBLK), dim3(NTHR),
                             args, 0, stream);
}

// Round 4
// 101599.701 us; speedup vs baseline: 4.2216x; 4.2216x over previous
//
#include <hip/hip_runtime.h>

// ---------------- ws float offsets (no aliasing; all zeroed each call) ----------------
#define OFF_PRE   0u            // [400][32][256]
#define OFF_PMT   3276800u      // [32][128][400]
#define OFF_GATT  4915200u      // [16][32][4096]
#define OFF_GDEC  7012352u      // [16][32][4096]
#define OFF_AH    9109504u
#define OFF_AC    9142272u
#define OFF_DH    9175040u
#define OFF_DC    9207808u
#define OFF_AW    9240576u      // [32][400]
#define OFF_AWC   9253376u
#define OFF_CTX   9266176u      // [32][512]
#define WS_TOTAL  9282560u      // 37.13 MB (< 37.65 MB proven in R1)

__device__ __forceinline__ float sigm(float x){ return 1.f/(1.f+__expf(-x)); }
__device__ __forceinline__ float ftanh(float x){
  x = fminf(fmaxf(x,-15.f),15.f);
  float e = __expf(2.f*x);
  return (e-1.f)/(e+1.f);
}

// -------------------- precompute --------------------

__global__ void zero_kernel(float* p, unsigned n){
  unsigned i = blockIdx.x*256u + threadIdx.x;
  if (i<n) p[i]=0.f;
}

// pre[(t*32+b)*256 + j] = relu(relu(dec_in @ W1) @ W2)
__global__ __launch_bounds__(256) void prenet_kernel(const float* __restrict__ mel_target,
    const float* __restrict__ W1, const float* __restrict__ W2, float* __restrict__ pre)
{
  __shared__ float din[80];
  __shared__ float h1[256];
  int blk = blockIdx.x;          // t*32 + b
  int t = blk >> 5, b = blk & 31;
  int tid = threadIdx.x;
  if (tid < 80) din[tid] = (t==0) ? 0.f : mel_target[b*32000 + tid*400 + (t-1)];
  __syncthreads();
  float s=0.f;
  for (int c=0;c<80;c++) s += din[c]*W1[c*256+tid];
  h1[tid] = fmaxf(s,0.f);
  __syncthreads();
  float s2=0.f;
  for (int c=0;c<256;c++) s2 += h1[c]*W2[c*256+tid];
  pre[(size_t)blk*256 + tid] = fmaxf(s2,0.f);
}

// pmT[b][a][t] = sum_d memory[b][t][d]*memory_W[d][a]  (direct transposed write)
__global__ __launch_bounds__(128) void pm_kernel(const float* __restrict__ memory,
    const float* __restrict__ memory_W, float* __restrict__ pmT)
{
  __shared__ float mrow[512];
  int blk = blockIdx.x;          // b*400 + t
  int b = blk/400, t = blk - b*400;
  int tid = threadIdx.x;
  const float* src = memory + (size_t)blk*512;
  for (int i=tid;i<512;i+=128) mrow[i]=src[i];
  __syncthreads();
  float s=0.f;
  for (int d=0; d<512; d++) s += mrow[d]*memory_W[d*128+tid];
  pmT[(size_t)b*51200 + tid*400 + t] = s;
}

// -------------------- per-step kernels --------------------

// Gates GEMM partials: x=concat(x0,x1,x2)[32][K] @ [Wih;Whh][K][4096] -> Gp[16][32][4096]
// grid (32 colblocks of 128, 16 k-slices), block 512 = 16 rowgroups(2r) x 32 colgroups(4c)
__global__ __launch_bounds__(512) void gates_kernel(
    const float* __restrict__ x0, int n0,
    const float* __restrict__ x1, int n1,
    const float* __restrict__ x2, int n2,
    const float* __restrict__ Wih, const float* __restrict__ Whh, int kih,
    float* __restrict__ Gp, int slice)
{
  extern __shared__ float xs[];   // [slice][33]
  const int tid = threadIdx.x;
  const int k_beg = blockIdx.y * slice;
  const int k_end = k_beg + slice;
  const int n01 = n0 + n1;
  // stage x slice: xs[kk*33 + r]
  for (int r=0; r<32; r++){
    for (int kk=tid; kk<slice; kk+=512){
      int k = k_beg + kk;
      float v;
      if (k < n0) v = x0[r*n0 + k];
      else if (k < n01) v = x1[r*n1 + (k-n0)];
      else v = x2[r*n2 + (k-n01)];
      xs[kk*33 + r] = v;
    }
  }
  __syncthreads();
  const int rg = tid >> 5;            // 0..15 -> rows rg*2, rg*2+1
  const int cg = tid & 31;            // 4 cols
  const int r0 = rg*2;
  const int colb = blockIdx.x*128 + cg*4;
  float4 a0 = {0,0,0,0}, a1 = {0,0,0,0};
  const int kA = (k_end < kih) ? k_end : kih;   // end of Wih part
  const int kB = (k_beg > kih) ? k_beg : kih;   // start of Whh part
  #pragma unroll 4
  for (int k=k_beg; k<kA; k++){
    float4 w = *(const float4*)(Wih + (size_t)k*4096 + colb);
    int kk = k - k_beg;
    float xv0 = xs[kk*33 + r0];
    float xv1 = xs[kk*33 + r0 + 1];
    a0.x += xv0*w.x; a0.y += xv0*w.y; a0.z += xv0*w.z; a0.w += xv0*w.w;
    a1.x += xv1*w.x; a1.y += xv1*w.y; a1.z += xv1*w.z; a1.w += xv1*w.w;
  }
  #pragma unroll 4
  for (int k=kB; k<k_end; k++){
    float4 w = *(const float4*)(Whh + (size_t)(k-kih)*4096 + colb);
    int kk = k - k_beg;
    float xv0 = xs[kk*33 + r0];
    float xv1 = xs[kk*33 + r0 + 1];
    a0.x += xv0*w.x; a0.y += xv0*w.y; a0.z += xv0*w.z; a0.w += xv0*w.w;
    a1.x += xv1*w.x; a1.y += xv1*w.y; a1.z += xv1*w.z; a1.w += xv1*w.w;
  }
  float* gp = Gp + (size_t)blockIdx.y*131072 + colb;
  *(float4*)(gp + (size_t)(r0  )*4096) = a0;
  *(float4*)(gp + (size_t)(r0+1)*4096) = a1;
}

// att: reduce partials + LSTM pw + q + conv + energies + softmax + aw/awc/aligns
// grid 32 (=b), block 512
__global__ __launch_bounds__(512) void att_mid_kernel(
    const float* __restrict__ Gp, const float* __restrict__ att_b,
    float* __restrict__ AH, float* __restrict__ AC,
    const float* __restrict__ query_W,
    const float* __restrict__ wc, const float* __restrict__ wd,
    const float* __restrict__ vvec, const float* __restrict__ pmT,
    const int* __restrict__ mlen,
    float* __restrict__ AW, float* __restrict__ AWC,
    float* __restrict__ aligns, int step)
{
  __shared__ float ah_s[1024];
  __shared__ float qp[512];
  __shared__ float q_s[128], v_s[128];
  __shared__ float aw_s[400], awc_s[400];
  __shared__ float wc_s[1984];
  __shared__ float wd_s[4096];
  __shared__ float red[16];
  const int b = blockIdx.x, tid = threadIdx.x;

  // stage small tensors
  for (int i=tid;i<400;i+=512){ aw_s[i]=AW[b*400+i]; awc_s[i]=AWC[b*400+i]; }
  for (int i=tid;i<4096;i+=512) wd_s[i]=wd[i];
  for (int i=tid;i<1984;i+=512) wc_s[i]=wc[i];
  if (tid<128) v_s[tid]=vvec[tid];

  // reduce 16 partials + LSTM pointwise
  for (int u=0; u<2; u++){
    int j = tid + u*512;
    float gi=att_b[j], gf=att_b[1024+j], gg=att_b[2048+j], go=att_b[3072+j];
    for (int s=0; s<16; s++){
      const float* g = Gp + (size_t)s*131072 + (size_t)b*4096;
      gi+=g[j]; gf+=g[1024+j]; gg+=g[2048+j]; go+=g[3072+j];
    }
    float c = sigm(gf)*AC[b*1024+j] + sigm(gi)*ftanh(gg);
    float h = sigm(go)*ftanh(c);
    AC[b*1024+j]=c; AH[b*1024+j]=h; ah_s[j]=h;
  }
  __syncthreads();
  // q = ah @ query_W (4-way K split)
  { int a = tid & 127, sl = tid >> 7;
    float s=0.f; int kb = sl*256;
    for (int k=kb;k<kb+256;k++) s += ah_s[k]*query_W[k*128+a];
    qp[sl*128+a]=s; }
  __syncthreads();
  if (tid<128) q_s[tid] = qp[tid]+qp[128+tid]+qp[256+tid]+qp[384+tid];
  __syncthreads();

  // energies: thread t
  float ev = -1e30f;
  const int t = tid;
  if (t < 400 && t < mlen[b]){
    float cf[32];
    #pragma unroll
    for (int f=0;f<32;f++) cf[f]=0.f;
    for (int k=0;k<31;k++){
      int gi2 = t + k - 15;
      float a1 = (gi2>=0 && gi2<400) ? aw_s[gi2] : 0.f;
      float a2 = (gi2>=0 && gi2<400) ? awc_s[gi2] : 0.f;
      #pragma unroll
      for (int f=0;f<32;f++)
        cf[f] += wc_s[f*62 + k]*a1 + wc_s[f*62 + 31 + k]*a2;
    }
    float acc=0.f;
    const float* pmrow = pmT + (size_t)b*51200 + t;   // stride 400 along a -> lane-coalesced
    for (int a=0;a<128;a++){
      float lv=0.f;
      #pragma unroll
      for (int f=0;f<32;f++) lv += cf[f]*wd_s[f*128+a];
      acc += ftanh(q_s[a] + pmrow[(size_t)a*400] + lv)*v_s[a];
    }
    ev = acc;
  }
  // block softmax over 400 (512 threads, 8 waves)
  float m = ev;
  for (int off=32; off>0; off>>=1) m = fmaxf(m, __shfl_down(m, off, 64));
  if ((tid&63)==0) red[tid>>6]=m;
  __syncthreads();
  if (tid==0){ float mm=red[0]; for (int i=1;i<8;i++) mm=fmaxf(mm,red[i]); red[8]=mm; }
  __syncthreads();
  m = red[8];
  float ex = (tid<400) ? __expf(ev-m) : 0.f;
  float ss = ex;
  for (int off=32; off>0; off>>=1) ss += __shfl_down(ss, off, 64);
  if ((tid&63)==0) red[tid>>6]=ss;
  __syncthreads();
  if (tid==0){ float s2=0.f; for (int i=0;i<8;i++) s2+=red[i]; red[9]=1.f/s2; }
  __syncthreads();
  float anew = ex*red[9];
  if (tid<400){
    AW[b*400+tid] = anew;
    AWC[b*400+tid] = awc_s[tid] + anew;
    aligns[(size_t)b*160000 + step*400 + tid] = anew;
  }
}

// ctx[b][d] = sum_t aw[t]*memory[b][t][d]: grid (32, 8 dchunks), block 256
__global__ __launch_bounds__(256) void ctx_kernel(
    const float* __restrict__ AW, const float* __restrict__ memory,
    float* __restrict__ CTX)
{
  __shared__ float aw_s[400];
  __shared__ float cp[256];
  int b = blockIdx.x, d0 = blockIdx.y*64, tid = threadIdx.x;
  for (int i=tid;i<400;i+=256) aw_s[i]=AW[b*400+i];
  __syncthreads();
  int d = tid & 63, ts = tid >> 6;       // 4 t-slices of 100
  const float* mrow = memory + (size_t)b*204800 + d0 + d;
  float p=0.f;
  for (int tt=ts*100; tt<ts*100+100; tt++) p += aw_s[tt]*mrow[(size_t)tt*512];
  cp[ts*64+d]=p;
  __syncthreads();
  if (tid<64){
    CTX[b*512+d0+tid] = cp[tid]+cp[64+tid]+cp[128+tid]+cp[192+tid];
  }
}

// dec: reduce partials + LSTM pw + projections. grid 32, block 512
__global__ __launch_bounds__(512) void dec_rest_kernel(
    const float* __restrict__ Gp, const float* __restrict__ dec_b,
    float* __restrict__ DH, float* __restrict__ DC,
    const float* __restrict__ CTX,
    const float* __restrict__ proj_W, const float* __restrict__ proj_b,
    const float* __restrict__ gate_W, const float* __restrict__ gate_b,
    float* __restrict__ out, int step)
{
  __shared__ float do_s[1536];
  __shared__ float pp[6*81];
  int b = blockIdx.x, tid = threadIdx.x;
  for (int u=0;u<2;u++){
    int j = tid + u*512;
    float gi=dec_b[j], gf=dec_b[1024+j], gg=dec_b[2048+j], go=dec_b[3072+j];
    for (int s=0;s<16;s++){
      const float* g = Gp + (size_t)s*131072 + (size_t)b*4096;
      gi+=g[j]; gf+=g[1024+j]; gg+=g[2048+j]; go+=g[3072+j];
    }
    float c = sigm(gf)*DC[b*1024+j] + sigm(gi)*ftanh(gg);
    float h = sigm(go)*ftanh(c);
    DC[b*1024+j]=c; DH[b*1024+j]=h; do_s[j]=h;
  }
  do_s[1024+tid] = CTX[b*512+tid];
  __syncthreads();
  int sl = tid/81, o = tid - sl*81;   // 6 K-slices x 81 outputs
  if (sl < 6){
    float s=0.f; int kb = sl*256;
    for (int k=kb;k<kb+256;k++){
      float w2 = (o<80) ? proj_W[k*80+o] : gate_W[k];
      s += do_s[k]*w2;
    }
    pp[sl*81+o]=s;
  }
  __syncthreads();
  if (tid<81){
    float r=0.f;
    for (int s2=0;s2<6;s2++) r += pp[s2*81+tid];
    if (tid<80) out[(size_t)b*32000 + tid*400 + step] = r + proj_b[tid];
    else        out[1024000 + b*400 + step] = r + gate_b[0];
  }
}

// -------------------- launch --------------------

extern "C" void kernel_launch(void* const* d_in, const int* in_sizes, int n_in,
                              void* d_out, int out_size, void* d_ws, size_t ws_size,
                              hipStream_t stream) {
  const float* memory      = (const float*)d_in[0];
  const float* mel_target  = (const float*)d_in[1];
  const int*   mlen        = (const int*)  d_in[2];
  const float* prenet_W1   = (const float*)d_in[3];
  const float* prenet_W2   = (const float*)d_in[4];
  const float* query_W     = (const float*)d_in[5];
  const float* memory_W    = (const float*)d_in[6];
  const float* weight_vec  = (const float*)d_in[7];
  const float* loc_conv_W  = (const float*)d_in[8];
  const float* loc_dense_W = (const float*)d_in[9];
  const float* att_Wih     = (const float*)d_in[10];
  const float* att_Whh     = (const float*)d_in[11];
  const float* att_b       = (const float*)d_in[12];
  const float* dec_Wih     = (const float*)d_in[13];
  const float* dec_Whh     = (const float*)d_in[14];
  const float* dec_b       = (const float*)d_in[15];
  const float* proj_W      = (const float*)d_in[16];
  const float* proj_b      = (const float*)d_in[17];
  const float* gate_W      = (const float*)d_in[18];
  const float* gate_b      = (const float*)d_in[19];
  float* out = (float*)d_out;
  float* ws  = (float*)d_ws;

  float* PRE  = ws + OFF_PRE;
  float* PMT  = ws + OFF_PMT;
  float* GATT = ws + OFF_GATT;
  float* GDEC = ws + OFF_GDEC;
  float* AH   = ws + OFF_AH;
  float* AC   = ws + OFF_AC;
  float* DH   = ws + OFF_DH;
  float* DC   = ws + OFF_DC;
  float* AW   = ws + OFF_AW;
  float* AWC  = ws + OFF_AWC;
  float* CTX  = ws + OFF_CTX;
  float* aligns = out + 1036800;

  // zero the entire used workspace every call -> replays bitwise-identical
  hipLaunchKernelGGL(zero_kernel, dim3((WS_TOTAL+255u)/256u), dim3(256), 0, stream, ws, WS_TOTAL);
  hipLaunchKernelGGL(prenet_kernel, dim3(12800), dim3(256), 0, stream,
                     mel_target, prenet_W1, prenet_W2, PRE);
  hipLaunchKernelGGL(pm_kernel, dim3(12800), dim3(128), 0, stream, memory, memory_W, PMT);

  const size_t lds_att = 112*33*sizeof(float);
  const size_t lds_dec = 160*33*sizeof(float);

  for (int t=0; t<400; t++){
    // attention LSTM gates: K=1792 = 16 x 112
    hipLaunchKernelGGL(gates_kernel, dim3(32,16), dim3(512), lds_att, stream,
        PRE + (size_t)t*8192, 256, CTX, 512, AH, 1024,
        att_Wih, att_Whh, 768, GATT, 112);
    hipLaunchKernelGGL(att_mid_kernel, dim3(32), dim3(512), 0, stream,
        GATT, att_b, AH, AC, query_W, loc_conv_W, loc_dense_W, weight_vec,
        PMT, mlen, AW, AWC, aligns, t);
    hipLaunchKernelGGL(ctx_kernel, dim3(32,8), dim3(256), 0, stream,
        AW, memory, CTX);
    // decoder LSTM gates: K=2560 = 16 x 160
    hipLaunchKernelGGL(gates_kernel, dim3(32,16), dim3(512), lds_dec, stream,
        AH, 1024, CTX, 512, DH, 1024,
        dec_Wih, dec_Whh, 1536, GDEC, 160);
    hipLaunchKernelGGL(dec_rest_kernel, dim3(32), dim3(512), 0, stream,
        GDEC, dec_b, DH, DC, CTX, proj_W, proj_b, gate_W, gate_b, out, t);
  }
}

// Round 5
// 80381.268 us; speedup vs baseline: 5.3360x; 1.2640x over previous
//
#include <hip/hip_runtime.h>

// ---------------- ws float offsets ----------------
#define OFF_PRE   0u            // [400][32][256]
#define OFF_PMT   3276800u      // [32][128][400]
#define OFF_GATT  4915200u      // [8][32][4096]
#define OFF_GDEC  5963776u      // [16][32][4096]
#define OFF_E     8060928u      // [32][400]
#define OFF_AH    8073728u
#define OFF_AC0   8106496u
#define OFF_AC1   8139264u
#define OFF_DH    8172032u
#define OFF_DC    8204800u
#define OFF_AW0   8237568u
#define OFF_AW1   8250368u
#define OFF_AWC0  8263168u
#define OFF_AWC1  8275968u
#define OFF_CTX0  8288768u
#define OFF_CTX1  8305152u
#define WS_TOTAL  8321536u      // 33.3 MB

__device__ __forceinline__ float sigm(float x){ return 1.f/(1.f+__expf(-x)); }
__device__ __forceinline__ float ftanh(float x){
  x = fminf(fmaxf(x,-15.f),15.f);
  float e = __expf(2.f*x);
  return (e-1.f)/(e+1.f);
}

// -------------------- precompute --------------------

__global__ void zero_kernel(float* p, unsigned n){
  unsigned i = blockIdx.x*256u + threadIdx.x;
  if (i<n) p[i]=0.f;
}

__global__ __launch_bounds__(256) void prenet_kernel(const float* __restrict__ mel_target,
    const float* __restrict__ W1, const float* __restrict__ W2, float* __restrict__ pre)
{
  __shared__ float din[80];
  __shared__ float h1[256];
  int blk = blockIdx.x;          // t*32 + b
  int t = blk >> 5, b = blk & 31;
  int tid = threadIdx.x;
  if (tid < 80) din[tid] = (t==0) ? 0.f : mel_target[b*32000 + tid*400 + (t-1)];
  __syncthreads();
  float s=0.f;
  for (int c=0;c<80;c++) s += din[c]*W1[c*256+tid];
  h1[tid] = fmaxf(s,0.f);
  __syncthreads();
  float s2=0.f;
  for (int c=0;c<256;c++) s2 += h1[c]*W2[c*256+tid];
  pre[(size_t)blk*256 + tid] = fmaxf(s2,0.f);
}

// pmT[b][a][t] = sum_d memory[b][t][d]*memory_W[d][a]
__global__ __launch_bounds__(128) void pm_kernel(const float* __restrict__ memory,
    const float* __restrict__ memory_W, float* __restrict__ pmT)
{
  __shared__ float mrow[512];
  int blk = blockIdx.x;          // b*400 + t
  int b = blk/400, t = blk - b*400;
  int tid = threadIdx.x;
  const float* src = memory + (size_t)blk*512;
  for (int i=tid;i<512;i+=128) mrow[i]=src[i];
  __syncthreads();
  float s=0.f;
  for (int d=0; d<512; d++) s += mrow[d]*memory_W[d*128+tid];
  pmT[(size_t)b*51200 + tid*400 + t] = s;
}

// -------------------- gates GEMM --------------------
// x=concat(x0,x1,x2)[32][K] @ [Wih;Whh][K][4096] -> Gp[NS][32][4096]
// grid (32 colblocks of 128, NS k-slices), block 512 = 16 rowgroups(2r) x 32 colgroups(4c)
template<int SLICE, int KIH>
__global__ __launch_bounds__(512) void gates_kernel(
    const float* __restrict__ x0, int n0,
    const float* __restrict__ x1, int n1,
    const float* __restrict__ x2, int n2,
    const float* __restrict__ Wih, const float* __restrict__ Whh,
    float* __restrict__ Gp)
{
  __shared__ float xs[SLICE*33];
  const int tid = threadIdx.x;
  const int k_beg = blockIdx.y * SLICE;
  const int k_end = k_beg + SLICE;
  const int n01 = n0 + n1;
  for (int base=0; base<32*SLICE; base+=512){
    int idx = base + tid;
    if (idx < 32*SLICE){
      int r = idx / SLICE, kk = idx - r*SLICE;
      int k = k_beg + kk;
      float v;
      if (k < n0) v = x0[r*n0 + k];
      else if (k < n01) v = x1[r*n1 + (k-n0)];
      else v = x2[r*n2 + (k-n01)];
      xs[kk*33 + r] = v;
    }
  }
  __syncthreads();
  const int rg = tid >> 5, cg = tid & 31;
  const int r0 = rg*2;
  const int colb = blockIdx.x*128 + cg*4;
  float4 a0 = {0,0,0,0}, a1 = {0,0,0,0};
  const int kA = (k_end < KIH) ? k_end : KIH;
  const int kB = (k_beg > KIH) ? k_beg : KIH;
  #pragma unroll 4
  for (int k=k_beg; k<kA; k++){
    float4 w = *(const float4*)(Wih + (size_t)k*4096 + colb);
    int kk = k - k_beg;
    float xv0 = xs[kk*33 + r0], xv1 = xs[kk*33 + r0 + 1];
    a0.x += xv0*w.x; a0.y += xv0*w.y; a0.z += xv0*w.z; a0.w += xv0*w.w;
    a1.x += xv1*w.x; a1.y += xv1*w.y; a1.z += xv1*w.z; a1.w += xv1*w.w;
  }
  #pragma unroll 4
  for (int k=kB; k<k_end; k++){
    float4 w = *(const float4*)(Whh + (size_t)(k-KIH)*4096 + colb);
    int kk = k - k_beg;
    float xv0 = xs[kk*33 + r0], xv1 = xs[kk*33 + r0 + 1];
    a0.x += xv0*w.x; a0.y += xv0*w.y; a0.z += xv0*w.z; a0.w += xv0*w.w;
    a1.x += xv1*w.x; a1.y += xv1*w.y; a1.z += xv1*w.z; a1.w += xv1*w.w;
  }
  float* gp = Gp + (size_t)blockIdx.y*131072 + colb;
  *(float4*)(gp + (size_t)(r0  )*4096) = a0;
  *(float4*)(gp + (size_t)(r0+1)*4096) = a1;
}

// -------------------- K2: att middle (grid 32 x 8, 512 thr) --------------------
// per (b, chunk): reduce GATT + att-LSTM pw (+write state if yD==0) + q (redundant)
// + conv+energies for its 50-t chunk + distributed dec pointwise of step t-1.
__global__ __launch_bounds__(512) void att_mid_kernel(
    const float* __restrict__ Gp, const float* __restrict__ att_b,
    float* __restrict__ AH, const float* __restrict__ ACr, float* __restrict__ ACw,
    const float* __restrict__ query_W,
    const float* __restrict__ wc, const float* __restrict__ wd,
    const float* __restrict__ vvec, const float* __restrict__ pmT,
    const int* __restrict__ mlen,
    const float* __restrict__ AWr, const float* __restrict__ AWCr,
    float* __restrict__ E,
    const float* __restrict__ Gd, const float* __restrict__ dec_b,
    float* __restrict__ DH, float* __restrict__ DC,
    int step)
{
  __shared__ float aw_s[400], awc_s[400];
  __shared__ float wc_s[1984];
  __shared__ float wd_s[4096];
  __shared__ float v_s[128], q_s[128];
  __shared__ float ah_s[1024];
  __shared__ float pool[4608];
  const int b = blockIdx.x, yD = blockIdx.y, tid = threadIdx.x;

  for (int i=tid;i<400;i+=512){ aw_s[i]=AWr[b*400+i]; awc_s[i]=AWCr[b*400+i]; }
  for (int i=tid;i<4096;i+=512) wd_s[i]=wd[i];
  for (int i=tid;i<1984;i+=512) wc_s[i]=wc[i];
  if (tid<128) v_s[tid]=vvec[tid];

  // reduce att gate partials (8 slices) into pool (as float4)
  {
    float4* g4 = (float4*)pool;
    for (int i=tid; i<1024; i+=512){
      float4 s = {0,0,0,0};
      #pragma unroll
      for (int sl=0; sl<8; sl++){
        const float4* gs = (const float4*)(Gp + (size_t)sl*131072 + (size_t)b*4096);
        float4 v = gs[i];
        s.x+=v.x; s.y+=v.y; s.z+=v.z; s.w+=v.w;
      }
      g4[i] = s;
    }
  }
  __syncthreads();
  // att LSTM pointwise (redundant; yD==0 writes state)
  for (int u0=0; u0<2; u0++){
    int u = tid + u0*512;
    float gi=pool[u]+att_b[u], gf=pool[1024+u]+att_b[1024+u];
    float gg=pool[2048+u]+att_b[2048+u], go=pool[3072+u]+att_b[3072+u];
    float c = sigm(gf)*ACr[b*1024+u] + sigm(gi)*ftanh(gg);
    float h = sigm(go)*ftanh(c);
    ah_s[u]=h;
    if (yD==0){ ACw[b*1024+u]=c; AH[b*1024+u]=h; }
  }
  __syncthreads();
  // q = ah @ query_W (4-way K split), qp in pool[0..512)
  { int a = tid & 127, sl = tid >> 7;
    float s=0.f; int kb = sl*256;
    for (int k=kb;k<kb+256;k++) s += ah_s[k]*query_W[k*128+a];
    pool[sl*128+a]=s; }
  __syncthreads();
  if (tid<128) q_s[tid] = pool[tid]+pool[128+tid]+pool[256+tid]+pool[384+tid];
  // distributed dec pointwise of step t-1 (units yD*128..+128)
  if (step>0 && tid<128){
    int u = yD*128 + tid;
    float gi=dec_b[u], gf=dec_b[1024+u], gg=dec_b[2048+u], go=dec_b[3072+u];
    #pragma unroll
    for (int sl=0; sl<16; sl++){
      const float* g = Gd + (size_t)sl*131072 + (size_t)b*4096;
      gi+=g[u]; gf+=g[1024+u]; gg+=g[2048+u]; go+=g[3072+u];
    }
    float c = sigm(gf)*DC[b*1024+u] + sigm(gi)*ftanh(gg);
    float h = sigm(go)*ftanh(c);
    DC[b*1024+u]=c; DH[b*1024+u]=h;
  }
  __syncthreads();
  // conv location features for chunk (50 t), loc = pool[512..512+1650)
  const int t0 = yD*50;
  float* loc = pool + 512;
  { int tl = tid & 63, fs = tid >> 6;
    if (tl < 50){
      float cf0=0,cf1=0,cf2=0,cf3=0;
      int f0 = fs*4;
      int tg = t0 + tl;
      for (int k=0;k<31;k++){
        int gi2 = tg + k - 15;
        float a1 = (gi2>=0 && gi2<400) ? aw_s[gi2] : 0.f;
        float a2 = (gi2>=0 && gi2<400) ? awc_s[gi2] : 0.f;
        cf0 += wc_s[(f0+0)*62+k]*a1 + wc_s[(f0+0)*62+31+k]*a2;
        cf1 += wc_s[(f0+1)*62+k]*a1 + wc_s[(f0+1)*62+31+k]*a2;
        cf2 += wc_s[(f0+2)*62+k]*a1 + wc_s[(f0+2)*62+31+k]*a2;
        cf3 += wc_s[(f0+3)*62+k]*a1 + wc_s[(f0+3)*62+31+k]*a2;
      }
      loc[tl*33+f0+0]=cf0; loc[tl*33+f0+1]=cf1;
      loc[tl*33+f0+2]=cf2; loc[tl*33+f0+3]=cf3;
    }
  }
  __syncthreads();
  // energies for chunk: wave = a-slice of 16, lanes = t
  float* ep = pool + 2176;
  { int tl = tid & 63, as = tid >> 6;
    if (tl < 50){
      int tg = t0 + tl;
      float e = 0.f;
      const float* lrow = loc + tl*33;
      for (int aa=0; aa<16; aa++){
        int a = as*16 + aa;
        float pmv = pmT[(size_t)b*51200 + (size_t)a*400 + tg];
        float lv = 0.f;
        #pragma unroll
        for (int f=0; f<32; f++) lv += lrow[f]*wd_s[f*128+a];
        e += ftanh(q_s[a]+pmv+lv)*v_s[a];
      }
      ep[as*64+tl] = e;
    }
  }
  __syncthreads();
  if (tid < 50){
    int tg = t0 + tid;
    float ee=0.f;
    #pragma unroll
    for (int as2=0; as2<8; as2++) ee += ep[as2*64+tid];
    E[b*400+tg] = (tg < mlen[b]) ? ee : -1e30f;
  }
}

// -------------------- K3: softmax + ctx + (proj of t-1 on yD==0) --------------------
__global__ __launch_bounds__(512) void softmax_ctx_kernel(
    const float* __restrict__ E, const float* __restrict__ memory,
    float* __restrict__ AWw, const float* __restrict__ AWCr, float* __restrict__ AWCw,
    float* __restrict__ CTXw, const float* __restrict__ CTXpp,
    const float* __restrict__ DH,
    const float* __restrict__ proj_W, const float* __restrict__ proj_b,
    const float* __restrict__ gate_W, const float* __restrict__ gate_b,
    float* __restrict__ out, float* __restrict__ aligns, int step)
{
  __shared__ float e_s[400];
  __shared__ float red[16];
  __shared__ float cp[512];
  __shared__ float do_s[1536];
  __shared__ float pps[486];
  const int b = blockIdx.x, yD = blockIdx.y, tid = threadIdx.x;

  float ev = (tid<400) ? E[b*400+tid] : -1e30f;
  float m = ev;
  for (int off=32; off>0; off>>=1) m = fmaxf(m, __shfl_down(m, off, 64));
  if ((tid&63)==0) red[tid>>6]=m;
  __syncthreads();
  if (tid==0){ float mm=red[0]; for (int i=1;i<8;i++) mm=fmaxf(mm,red[i]); red[8]=mm; }
  __syncthreads();
  m = red[8];
  float ex = (tid<400) ? __expf(ev-m) : 0.f;
  float ss = ex;
  for (int off=32; off>0; off>>=1) ss += __shfl_down(ss, off, 64);
  if ((tid&63)==0) red[tid>>6]=ss;
  __syncthreads();
  if (tid==0){ float s2=0.f; for (int i=0;i<8;i++) s2+=red[i]; red[9]=1.f/s2; }
  __syncthreads();
  float anew = ex*red[9];
  if (tid<400) e_s[tid]=anew;
  if (yD==0 && tid<400){
    AWw[b*400+tid] = anew;
    AWCw[b*400+tid] = AWCr[b*400+tid] + anew;
    aligns[(size_t)b*160000 + (size_t)step*400 + tid] = anew;
  }
  __syncthreads();
  // ctx chunk
  { int d = tid & 63, ts = tid >> 6;
    const int d0 = yD*64;
    const float* mrow = memory + (size_t)b*204800 + d0 + d;
    float pacc=0.f;
    for (int tt=ts*50; tt<ts*50+50; tt++) pacc += e_s[tt]*mrow[(size_t)tt*512];
    cp[ts*64+d]=pacc; }
  __syncthreads();
  if (tid<64){
    float s2=0.f;
    #pragma unroll
    for (int ts2=0; ts2<8; ts2++) s2+=cp[ts2*64+tid];
    CTXw[b*512 + yD*64 + tid]=s2;
  }
  // projections for step-1 (yD==0 only)
  if (yD==0 && step>0){
    for (int i=tid; i<1536; i+=512)
      do_s[i] = (i<1024) ? DH[b*1024+i] : CTXpp[b*512 + (i-1024)];
    __syncthreads();
    int sl = tid/81, o = tid - sl*81;
    if (sl < 6){
      float s=0.f; int kb = sl*256;
      for (int k=kb;k<kb+256;k++){
        float w2 = (o<80) ? proj_W[k*80+o] : gate_W[k];
        s += do_s[k]*w2;
      }
      pps[sl*81+o]=s;
    }
    __syncthreads();
    if (tid<81){
      float r=0.f;
      #pragma unroll
      for (int s2=0;s2<6;s2++) r += pps[s2*81+tid];
      if (tid<80) out[(size_t)b*32000 + tid*400 + (step-1)] = r + proj_b[tid];
      else        out[1024000 + b*400 + (step-1)] = r + gate_b[0];
    }
  }
}

// -------------------- final dec step (t=399) --------------------
__global__ __launch_bounds__(512) void dec_final_kernel(
    const float* __restrict__ Gd, const float* __restrict__ dec_b,
    const float* __restrict__ DC, const float* __restrict__ CTX1,
    const float* __restrict__ proj_W, const float* __restrict__ proj_b,
    const float* __restrict__ gate_W, const float* __restrict__ gate_b,
    float* __restrict__ out)
{
  __shared__ float g_s[4096];
  __shared__ float do_s[1536];
  __shared__ float pps[486];
  const int b = blockIdx.x, tid = threadIdx.x;
  { float4* g4 = (float4*)g_s;
    for (int i=tid; i<1024; i+=512){
      float4 s={0,0,0,0};
      #pragma unroll
      for (int sl=0; sl<16; sl++){
        const float4* gs = (const float4*)(Gd + (size_t)sl*131072 + (size_t)b*4096);
        float4 v = gs[i];
        s.x+=v.x; s.y+=v.y; s.z+=v.z; s.w+=v.w;
      }
      g4[i]=s;
    } }
  __syncthreads();
  for (int u0=0; u0<2; u0++){
    int u = tid + u0*512;
    float gi=g_s[u]+dec_b[u], gf=g_s[1024+u]+dec_b[1024+u];
    float gg=g_s[2048+u]+dec_b[2048+u], go=g_s[3072+u]+dec_b[3072+u];
    float c = sigm(gf)*DC[b*1024+u] + sigm(gi)*ftanh(gg);
    do_s[u] = sigm(go)*ftanh(c);
  }
  if (tid<512) do_s[1024+tid] = CTX1[b*512+tid];
  __syncthreads();
  int sl = tid/81, o = tid - sl*81;
  if (sl < 6){
    float s=0.f; int kb = sl*256;
    for (int k=kb;k<kb+256;k++){
      float w2 = (o<80) ? proj_W[k*80+o] : gate_W[k];
      s += do_s[k]*w2;
    }
    pps[sl*81+o]=s;
  }
  __syncthreads();
  if (tid<81){
    float r=0.f;
    #pragma unroll
    for (int s2=0;s2<6;s2++) r += pps[s2*81+tid];
    if (tid<80) out[(size_t)b*32000 + tid*400 + 399] = r + proj_b[tid];
    else        out[1024000 + b*400 + 399] = r + gate_b[0];
  }
}

// -------------------- launch --------------------

extern "C" void kernel_launch(void* const* d_in, const int* in_sizes, int n_in,
                              void* d_out, int out_size, void* d_ws, size_t ws_size,
                              hipStream_t stream) {
  const float* memory      = (const float*)d_in[0];
  const float* mel_target  = (const float*)d_in[1];
  const int*   mlen        = (const int*)  d_in[2];
  const float* prenet_W1   = (const float*)d_in[3];
  const float* prenet_W2   = (const float*)d_in[4];
  const float* query_W     = (const float*)d_in[5];
  const float* memory_W    = (const float*)d_in[6];
  const float* weight_vec  = (const float*)d_in[7];
  const float* loc_conv_W  = (const float*)d_in[8];
  const float* loc_dense_W = (const float*)d_in[9];
  const float* att_Wih     = (const float*)d_in[10];
  const float* att_Whh     = (const float*)d_in[11];
  const float* att_b       = (const float*)d_in[12];
  const float* dec_Wih     = (const float*)d_in[13];
  const float* dec_Whh     = (const float*)d_in[14];
  const float* dec_b       = (const float*)d_in[15];
  const float* proj_W      = (const float*)d_in[16];
  const float* proj_b      = (const float*)d_in[17];
  const float* gate_W      = (const float*)d_in[18];
  const float* gate_b      = (const float*)d_in[19];
  float* out = (float*)d_out;
  float* ws  = (float*)d_ws;

  float* PRE  = ws + OFF_PRE;
  float* PMT  = ws + OFF_PMT;
  float* GATT = ws + OFF_GATT;
  float* GDEC = ws + OFF_GDEC;
  float* E    = ws + OFF_E;
  float* AH   = ws + OFF_AH;
  float* AC[2] = { ws + OFF_AC0, ws + OFF_AC1 };
  float* DH   = ws + OFF_DH;
  float* DC   = ws + OFF_DC;
  float* AW[2] = { ws + OFF_AW0, ws + OFF_AW1 };
  float* AWC[2]= { ws + OFF_AWC0, ws + OFF_AWC1 };
  float* CTX[2]= { ws + OFF_CTX0, ws + OFF_CTX1 };
  float* aligns = out + 1036800;

  hipLaunchKernelGGL(zero_kernel, dim3((WS_TOTAL+255u)/256u), dim3(256), 0, stream, ws, WS_TOTAL);
  hipLaunchKernelGGL(prenet_kernel, dim3(12800), dim3(256), 0, stream,
                     mel_target, prenet_W1, prenet_W2, PRE);
  hipLaunchKernelGGL(pm_kernel, dim3(12800), dim3(128), 0, stream, memory, memory_W, PMT);

  for (int t=0; t<400; t++){
    const int p = t & 1, pp = 1 - p;
    // K1: attention LSTM gates (K=1792, 8 slices of 224)
    hipLaunchKernelGGL((gates_kernel<224,768>), dim3(32,8), dim3(512), 0, stream,
        PRE + (size_t)t*8192, 256, CTX[pp], 512, AH, 1024,
        att_Wih, att_Whh, GATT);
    // K2: att middle + distributed dec pointwise of t-1
    hipLaunchKernelGGL(att_mid_kernel, dim3(32,8), dim3(512), 0, stream,
        GATT, att_b, AH, AC[pp], AC[p], query_W, loc_conv_W, loc_dense_W,
        weight_vec, PMT, mlen, AW[pp], AWC[pp], E,
        GDEC, dec_b, DH, DC, t);
    // K3: softmax + ctx + projections of t-1
    hipLaunchKernelGGL(softmax_ctx_kernel, dim3(32,8), dim3(512), 0, stream,
        E, memory, AW[p], AWC[pp], AWC[p], CTX[p], CTX[pp],
        DH, proj_W, proj_b, gate_W, gate_b, out, aligns, t);
    // K4: decoder LSTM gates (K=2560, 16 slices of 160)
    hipLaunchKernelGGL((gates_kernel<160,1536>), dim3(32,16), dim3(512), 0, stream,
        AH, 1024, CTX[p], 512, DH, 1024,
        dec_Wih, dec_Whh, GDEC);
  }
  hipLaunchKernelGGL(dec_final_kernel, dim3(32), dim3(512), 0, stream,
      GDEC, dec_b, DC, CTX[1], proj_W, proj_b, gate_W, gate_b, out);
}

// Round 6
// 71895.355 us; speedup vs baseline: 5.9658x; 1.1180x over previous
//
#include <hip/hip_runtime.h>

// ---------------- ws float offsets ----------------
#define OFF_PRE   0u            // [400][32][256]
#define OFF_PMT   3276800u      // [32][128][400]
#define OFF_GATT  4915200u      // [16][32][4096]
#define OFF_GDEC  7012352u      // [16][32][4096]
#define OFF_E     9109504u      // [32][400]
#define OFF_AH    9122304u
#define OFF_AC0   9155072u
#define OFF_AC1   9187840u
#define OFF_DH    9220608u
#define OFF_DC    9253376u
#define OFF_AW0   9286144u
#define OFF_AW1   9298944u
#define OFF_AWC0  9311744u
#define OFF_AWC1  9324544u
#define OFF_CTX0  9337344u
#define OFF_CTX1  9353728u
#define WS_TOTAL  9370112u      // 37.48 MB (< 37.66 MB used successfully in R1)

__device__ __forceinline__ float sigm(float x){ return 1.f/(1.f+__expf(-x)); }
__device__ __forceinline__ float ftanh(float x){
  x = fminf(fmaxf(x,-15.f),15.f);
  float e = __expf(2.f*x);
  return (e-1.f)/(e+1.f);
}

typedef const __attribute__((address_space(1))) unsigned int* gas_t;
typedef __attribute__((address_space(3))) unsigned int* las_t;

// -------------------- precompute --------------------

__global__ void zero_kernel(float* p, unsigned n){
  unsigned i = blockIdx.x*256u + threadIdx.x;
  if (i<n) p[i]=0.f;
}

__global__ __launch_bounds__(256) void prenet_kernel(const float* __restrict__ mel_target,
    const float* __restrict__ W1, const float* __restrict__ W2, float* __restrict__ pre)
{
  __shared__ float din[80];
  __shared__ float h1[256];
  int blk = blockIdx.x;          // t*32 + b
  int t = blk >> 5, b = blk & 31;
  int tid = threadIdx.x;
  if (tid < 80) din[tid] = (t==0) ? 0.f : mel_target[b*32000 + tid*400 + (t-1)];
  __syncthreads();
  float s=0.f;
  for (int c=0;c<80;c++) s += din[c]*W1[c*256+tid];
  h1[tid] = fmaxf(s,0.f);
  __syncthreads();
  float s2=0.f;
  for (int c=0;c<256;c++) s2 += h1[c]*W2[c*256+tid];
  pre[(size_t)blk*256 + tid] = fmaxf(s2,0.f);
}

// pmT[b][a][t] = sum_d memory[b][t][d]*memory_W[d][a]
__global__ __launch_bounds__(128) void pm_kernel(const float* __restrict__ memory,
    const float* __restrict__ memory_W, float* __restrict__ pmT)
{
  __shared__ float mrow[512];
  int blk = blockIdx.x;          // b*400 + t
  int b = blk/400, t = blk - b*400;
  int tid = threadIdx.x;
  const float* src = memory + (size_t)blk*512;
  for (int i=tid;i<512;i+=128) mrow[i]=src[i];
  __syncthreads();
  float s=0.f;
  for (int d=0; d<512; d++) s += mrow[d]*memory_W[d*128+tid];
  pmT[(size_t)b*51200 + tid*400 + t] = s;
}

// -------------------- gates GEMM v3: global_load_lds weight streaming --------------------
// x=concat(x0,x1,x2)[32][K] @ [Wih;Whh][K][4096] -> Gp[16][32][4096] partials
// grid (32 colblocks of 128, 16 k-slices of SLICE), block 512.
// Weight sub-tiles (16 k-rows x 128 cols = 8KB) streamed into LDS via
// global_load_lds, triple-buffered, counted vmcnt (never drained in loop).
template<int SLICE, int KIH>
__global__ __launch_bounds__(512) void gates_v3(
    const float* __restrict__ x0, int n0,
    const float* __restrict__ x1, int n1,
    const float* __restrict__ x2, int n2,
    const float* __restrict__ Wih, const float* __restrict__ Whh,
    float* __restrict__ Gp)
{
  constexpr int NT = SLICE/16;           // sub-tiles per slice
  __shared__ float xs[SLICE*33];
  __shared__ float wbuf[3*2048];         // 3 x 8KB weight buffers
  const int tid = threadIdx.x;
  const int k_beg = blockIdx.y * SLICE;
  const int n01 = n0 + n1;

  // stage x slice (xs[kk*33 + r]); ends with full-drain __syncthreads -> vmcnt=0
  for (int base=0; base<32*SLICE; base+=512){
    int idx = base + tid;
    if (idx < 32*SLICE){
      int r = idx / SLICE, kk = idx - r*SLICE;
      int k = k_beg + kk;
      float v;
      if (k < n0) v = x0[r*n0 + k];
      else if (k < n01) v = x1[r*n1 + (k-n0)];
      else v = x2[r*n2 + (k-n01)];
      xs[kk*33 + r] = v;
    }
  }
  __syncthreads();

  const int wv = tid >> 6, lane = tid & 63;
  const int fb = wv*1024 + lane*16;      // byte offset within an 8KB sub-tile
  const int kk_l = fb >> 9;              // sub-tile-local k row (row = 512B)
  const int inner = fb & 511;            // byte within the 128-col chunk
  const size_t colbB = (size_t)blockIdx.x*512;   // col-block byte offset

  auto STAGE = [&](int s){
    int k = k_beg + s*16 + kk_l;
    const char* row = (k < KIH) ? ((const char*)Wih + (size_t)k*16384)
                                : ((const char*)Whh + (size_t)(k-KIH)*16384);
    const char* g = row + colbB + inner;           // per-lane global addr
    float* l = &wbuf[(s%3)*2048 + wv*256];         // wave-uniform LDS base
    __builtin_amdgcn_global_load_lds((gas_t)g, (las_t)l, 16, 0, 0);
  };

  STAGE(0);
  STAGE(1);

  const int rg = tid >> 5, cg = tid & 31;
  const int r0 = rg*2;
  float4 a0 = {0,0,0,0}, a1 = {0,0,0,0};

  for (int s=0; s<NT; s++){
    asm volatile("s_barrier" ::: "memory");        // readers of buf[(s+2)%3] done
    if (s+2 < NT) STAGE(s+2);
    int rem = NT-1-s;
    if (rem >= 2)      asm volatile("s_waitcnt vmcnt(2)" ::: "memory");
    else if (rem == 1) asm volatile("s_waitcnt vmcnt(1)" ::: "memory");
    else               asm volatile("s_waitcnt vmcnt(0)" ::: "memory");
    asm volatile("s_barrier" ::: "memory");        // buf[s%3] ready for all waves
    const float* wb = &wbuf[(s%3)*2048];
    const float* xk = &xs[(s*16)*33];
    #pragma unroll
    for (int kk=0; kk<16; kk++){
      float4 w = *(const float4*)(wb + kk*128 + cg*4);
      float xv0 = xk[kk*33 + r0], xv1 = xk[kk*33 + r0 + 1];
      a0.x += xv0*w.x; a0.y += xv0*w.y; a0.z += xv0*w.z; a0.w += xv0*w.w;
      a1.x += xv1*w.x; a1.y += xv1*w.y; a1.z += xv1*w.z; a1.w += xv1*w.w;
    }
  }
  float* gp = Gp + (size_t)blockIdx.y*131072 + blockIdx.x*128 + cg*4;
  *(float4*)(gp + (size_t)(r0  )*4096) = a0;
  *(float4*)(gp + (size_t)(r0+1)*4096) = a1;
}

// -------------------- K2: att middle (grid 32 x 8, 512 thr) --------------------
__global__ __launch_bounds__(512) void att_mid_kernel(
    const float* __restrict__ Gp, const float* __restrict__ att_b,
    float* __restrict__ AH, const float* __restrict__ ACr, float* __restrict__ ACw,
    const float* __restrict__ query_W,
    const float* __restrict__ wc, const float* __restrict__ wd,
    const float* __restrict__ vvec, const float* __restrict__ pmT,
    const int* __restrict__ mlen,
    const float* __restrict__ AWr, const float* __restrict__ AWCr,
    float* __restrict__ E,
    const float* __restrict__ Gd, const float* __restrict__ dec_b,
    float* __restrict__ DH, float* __restrict__ DC,
    int step)
{
  __shared__ float aw_s[400], awc_s[400];
  __shared__ float wc_s[1984];
  __shared__ float wd_s[4096];
  __shared__ float v_s[128], q_s[128];
  __shared__ float ah_s[1024];
  __shared__ float pool[4608];
  const int b = blockIdx.x, yD = blockIdx.y, tid = threadIdx.x;

  for (int i=tid;i<400;i+=512){ aw_s[i]=AWr[b*400+i]; awc_s[i]=AWCr[b*400+i]; }
  for (int i=tid;i<4096;i+=512) wd_s[i]=wd[i];
  for (int i=tid;i<1984;i+=512) wc_s[i]=wc[i];
  if (tid<128) v_s[tid]=vvec[tid];

  // reduce att gate partials (16 slices) into pool (as float4)
  {
    float4* g4 = (float4*)pool;
    for (int i=tid; i<1024; i+=512){
      float4 s = {0,0,0,0};
      #pragma unroll
      for (int sl=0; sl<16; sl++){
        const float4* gs = (const float4*)(Gp + (size_t)sl*131072 + (size_t)b*4096);
        float4 v = gs[i];
        s.x+=v.x; s.y+=v.y; s.z+=v.z; s.w+=v.w;
      }
      g4[i] = s;
    }
  }
  __syncthreads();
  // att LSTM pointwise (redundant; yD==0 writes state)
  for (int u0=0; u0<2; u0++){
    int u = tid + u0*512;
    float gi=pool[u]+att_b[u], gf=pool[1024+u]+att_b[1024+u];
    float gg=pool[2048+u]+att_b[2048+u], go=pool[3072+u]+att_b[3072+u];
    float c = sigm(gf)*ACr[b*1024+u] + sigm(gi)*ftanh(gg);
    float h = sigm(go)*ftanh(c);
    ah_s[u]=h;
    if (yD==0){ ACw[b*1024+u]=c; AH[b*1024+u]=h; }
  }
  __syncthreads();
  // q = ah @ query_W (4-way K split), qp in pool[0..512)
  { int a = tid & 127, sl = tid >> 7;
    float s=0.f; int kb = sl*256;
    for (int k=kb;k<kb+256;k++) s += ah_s[k]*query_W[k*128+a];
    pool[sl*128+a]=s; }
  __syncthreads();
  if (tid<128) q_s[tid] = pool[tid]+pool[128+tid]+pool[256+tid]+pool[384+tid];
  // distributed dec pointwise of step t-1 (units yD*128..+128)
  if (step>0 && tid<128){
    int u = yD*128 + tid;
    float gi=dec_b[u], gf=dec_b[1024+u], gg=dec_b[2048+u], go=dec_b[3072+u];
    #pragma unroll
    for (int sl=0; sl<16; sl++){
      const float* g = Gd + (size_t)sl*131072 + (size_t)b*4096;
      gi+=g[u]; gf+=g[1024+u]; gg+=g[2048+u]; go+=g[3072+u];
    }
    float c = sigm(gf)*DC[b*1024+u] + sigm(gi)*ftanh(gg);
    float h = sigm(go)*ftanh(c);
    DC[b*1024+u]=c; DH[b*1024+u]=h;
  }
  __syncthreads();
  // conv location features for chunk (50 t)
  const int t0 = yD*50;
  float* loc = pool + 512;
  { int tl = tid & 63, fs = tid >> 6;
    if (tl < 50){
      float cf0=0,cf1=0,cf2=0,cf3=0;
      int f0 = fs*4;
      int tg = t0 + tl;
      for (int k=0;k<31;k++){
        int gi2 = tg + k - 15;
        float a1 = (gi2>=0 && gi2<400) ? aw_s[gi2] : 0.f;
        float a2 = (gi2>=0 && gi2<400) ? awc_s[gi2] : 0.f;
        cf0 += wc_s[(f0+0)*62+k]*a1 + wc_s[(f0+0)*62+31+k]*a2;
        cf1 += wc_s[(f0+1)*62+k]*a1 + wc_s[(f0+1)*62+31+k]*a2;
        cf2 += wc_s[(f0+2)*62+k]*a1 + wc_s[(f0+2)*62+31+k]*a2;
        cf3 += wc_s[(f0+3)*62+k]*a1 + wc_s[(f0+3)*62+31+k]*a2;
      }
      loc[tl*33+f0+0]=cf0; loc[tl*33+f0+1]=cf1;
      loc[tl*33+f0+2]=cf2; loc[tl*33+f0+3]=cf3;
    }
  }
  __syncthreads();
  // energies for chunk
  float* ep = pool + 2176;
  { int tl = tid & 63, as = tid >> 6;
    if (tl < 50){
      int tg = t0 + tl;
      float e = 0.f;
      const float* lrow = loc + tl*33;
      for (int aa=0; aa<16; aa++){
        int a = as*16 + aa;
        float pmv = pmT[(size_t)b*51200 + (size_t)a*400 + tg];
        float lv = 0.f;
        #pragma unroll
        for (int f=0; f<32; f++) lv += lrow[f]*wd_s[f*128+a];
        e += ftanh(q_s[a]+pmv+lv)*v_s[a];
      }
      ep[as*64+tl] = e;
    }
  }
  __syncthreads();
  if (tid < 50){
    int tg = t0 + tid;
    float ee=0.f;
    #pragma unroll
    for (int as2=0; as2<8; as2++) ee += ep[as2*64+tid];
    E[b*400+tg] = (tg < mlen[b]) ? ee : -1e30f;
  }
}

// -------------------- K3: softmax + ctx + (proj of t-1 on yD==0) --------------------
__global__ __launch_bounds__(512) void softmax_ctx_kernel(
    const float* __restrict__ E, const float* __restrict__ memory,
    float* __restrict__ AWw, const float* __restrict__ AWCr, float* __restrict__ AWCw,
    float* __restrict__ CTXw, const float* __restrict__ CTXpp,
    const float* __restrict__ DH,
    const float* __restrict__ proj_W, const float* __restrict__ proj_b,
    const float* __restrict__ gate_W, const float* __restrict__ gate_b,
    float* __restrict__ out, float* __restrict__ aligns, int step)
{
  __shared__ float e_s[400];
  __shared__ float red[16];
  __shared__ float cp[512];
  __shared__ float do_s[1536];
  __shared__ float pps[486];
  const int b = blockIdx.x, yD = blockIdx.y, tid = threadIdx.x;

  float ev = (tid<400) ? E[b*400+tid] : -1e30f;
  float m = ev;
  for (int off=32; off>0; off>>=1) m = fmaxf(m, __shfl_down(m, off, 64));
  if ((tid&63)==0) red[tid>>6]=m;
  __syncthreads();
  if (tid==0){ float mm=red[0]; for (int i=1;i<8;i++) mm=fmaxf(mm,red[i]); red[8]=mm; }
  __syncthreads();
  m = red[8];
  float ex = (tid<400) ? __expf(ev-m) : 0.f;
  float ss = ex;
  for (int off=32; off>0; off>>=1) ss += __shfl_down(ss, off, 64);
  if ((tid&63)==0) red[tid>>6]=ss;
  __syncthreads();
  if (tid==0){ float s2=0.f; for (int i=0;i<8;i++) s2+=red[i]; red[9]=1.f/s2; }
  __syncthreads();
  float anew = ex*red[9];
  if (tid<400) e_s[tid]=anew;
  if (yD==0 && tid<400){
    AWw[b*400+tid] = anew;
    AWCw[b*400+tid] = AWCr[b*400+tid] + anew;
    aligns[(size_t)b*160000 + (size_t)step*400 + tid] = anew;
  }
  __syncthreads();
  // ctx chunk
  { int d = tid & 63, ts = tid >> 6;
    const int d0 = yD*64;
    const float* mrow = memory + (size_t)b*204800 + d0 + d;
    float pacc=0.f;
    for (int tt=ts*50; tt<ts*50+50; tt++) pacc += e_s[tt]*mrow[(size_t)tt*512];
    cp[ts*64+d]=pacc; }
  __syncthreads();
  if (tid<64){
    float s2=0.f;
    #pragma unroll
    for (int ts2=0; ts2<8; ts2++) s2+=cp[ts2*64+tid];
    CTXw[b*512 + yD*64 + tid]=s2;
  }
  // projections for step-1 (yD==0 only)
  if (yD==0 && step>0){
    for (int i=tid; i<1536; i+=512)
      do_s[i] = (i<1024) ? DH[b*1024+i] : CTXpp[b*512 + (i-1024)];
    __syncthreads();
    int sl = tid/81, o = tid - sl*81;
    if (sl < 6){
      float s=0.f; int kb = sl*256;
      for (int k=kb;k<kb+256;k++){
        float w2 = (o<80) ? proj_W[k*80+o] : gate_W[k];
        s += do_s[k]*w2;
      }
      pps[sl*81+o]=s;
    }
    __syncthreads();
    if (tid<81){
      float r=0.f;
      #pragma unroll
      for (int s2=0;s2<6;s2++) r += pps[s2*81+tid];
      if (tid<80) out[(size_t)b*32000 + tid*400 + (step-1)] = r + proj_b[tid];
      else        out[1024000 + b*400 + (step-1)] = r + gate_b[0];
    }
  }
}

// -------------------- final dec step (t=399) --------------------
__global__ __launch_bounds__(512) void dec_final_kernel(
    const float* __restrict__ Gd, const float* __restrict__ dec_b,
    const float* __restrict__ DC, const float* __restrict__ CTX1,
    const float* __restrict__ proj_W, const float* __restrict__ proj_b,
    const float* __restrict__ gate_W, const float* __restrict__ gate_b,
    float* __restrict__ out)
{
  __shared__ float g_s[4096];
  __shared__ float do_s[1536];
  __shared__ float pps[486];
  const int b = blockIdx.x, tid = threadIdx.x;
  { float4* g4 = (float4*)g_s;
    for (int i=tid; i<1024; i+=512){
      float4 s={0,0,0,0};
      #pragma unroll
      for (int sl=0; sl<16; sl++){
        const float4* gs = (const float4*)(Gd + (size_t)sl*131072 + (size_t)b*4096);
        float4 v = gs[i];
        s.x+=v.x; s.y+=v.y; s.z+=v.z; s.w+=v.w;
      }
      g4[i]=s;
    } }
  __syncthreads();
  for (int u0=0; u0<2; u0++){
    int u = tid + u0*512;
    float gi=g_s[u]+dec_b[u], gf=g_s[1024+u]+dec_b[1024+u];
    float gg=g_s[2048+u]+dec_b[2048+u], go=g_s[3072+u]+dec_b[3072+u];
    float c = sigm(gf)*DC[b*1024+u] + sigm(gi)*ftanh(gg);
    do_s[u] = sigm(go)*ftanh(c);
  }
  if (tid<512) do_s[1024+tid] = CTX1[b*512+tid];
  __syncthreads();
  int sl = tid/81, o = tid - sl*81;
  if (sl < 6){
    float s=0.f; int kb = sl*256;
    for (int k=kb;k<kb+256;k++){
      float w2 = (o<80) ? proj_W[k*80+o] : gate_W[k];
      s += do_s[k]*w2;
    }
    pps[sl*81+o]=s;
  }
  __syncthreads();
  if (tid<81){
    float r=0.f;
    #pragma unroll
    for (int s2=0;s2<6;s2++) r += pps[s2*81+tid];
    if (tid<80) out[(size_t)b*32000 + tid*400 + 399] = r + proj_b[tid];
    else        out[1024000 + b*400 + 399] = r + gate_b[0];
  }
}

// -------------------- launch --------------------

extern "C" void kernel_launch(void* const* d_in, const int* in_sizes, int n_in,
                              void* d_out, int out_size, void* d_ws, size_t ws_size,
                              hipStream_t stream) {
  const float* memory      = (const float*)d_in[0];
  const float* mel_target  = (const float*)d_in[1];
  const int*   mlen        = (const int*)  d_in[2];
  const float* prenet_W1   = (const float*)d_in[3];
  const float* prenet_W2   = (const float*)d_in[4];
  const float* query_W     = (const float*)d_in[5];
  const float* memory_W    = (const float*)d_in[6];
  const float* weight_vec  = (const float*)d_in[7];
  const float* loc_conv_W  = (const float*)d_in[8];
  const float* loc_dense_W = (const float*)d_in[9];
  const float* att_Wih     = (const float*)d_in[10];
  const float* att_Whh     = (const float*)d_in[11];
  const float* att_b       = (const float*)d_in[12];
  const float* dec_Wih     = (const float*)d_in[13];
  const float* dec_Whh     = (const float*)d_in[14];
  const float* dec_b       = (const float*)d_in[15];
  const float* proj_W      = (const float*)d_in[16];
  const float* proj_b      = (const float*)d_in[17];
  const float* gate_W      = (const float*)d_in[18];
  const float* gate_b      = (const float*)d_in[19];
  float* out = (float*)d_out;
  float* ws  = (float*)d_ws;

  float* PRE  = ws + OFF_PRE;
  float* PMT  = ws + OFF_PMT;
  float* GATT = ws + OFF_GATT;
  float* GDEC = ws + OFF_GDEC;
  float* E    = ws + OFF_E;
  float* AH   = ws + OFF_AH;
  float* AC[2] = { ws + OFF_AC0, ws + OFF_AC1 };
  float* DH   = ws + OFF_DH;
  float* DC   = ws + OFF_DC;
  float* AW[2] = { ws + OFF_AW0, ws + OFF_AW1 };
  float* AWC[2]= { ws + OFF_AWC0, ws + OFF_AWC1 };
  float* CTX[2]= { ws + OFF_CTX0, ws + OFF_CTX1 };
  float* aligns = out + 1036800;

  hipLaunchKernelGGL(zero_kernel, dim3((WS_TOTAL+255u)/256u), dim3(256), 0, stream, ws, WS_TOTAL);
  hipLaunchKernelGGL(prenet_kernel, dim3(12800), dim3(256), 0, stream,
                     mel_target, prenet_W1, prenet_W2, PRE);
  hipLaunchKernelGGL(pm_kernel, dim3(12800), dim3(128), 0, stream, memory, memory_W, PMT);

  for (int t=0; t<400; t++){
    const int p = t & 1, pp = 1 - p;
    // K1: attention LSTM gates (K=1792 = 16 slices of 112)
    hipLaunchKernelGGL((gates_v3<112,768>), dim3(32,16), dim3(512), 0, stream,
        PRE + (size_t)t*8192, 256, CTX[pp], 512, AH, 1024,
        att_Wih, att_Whh, GATT);
    // K2: att middle + distributed dec pointwise of t-1
    hipLaunchKernelGGL(att_mid_kernel, dim3(32,8), dim3(512), 0, stream,
        GATT, att_b, AH, AC[pp], AC[p], query_W, loc_conv_W, loc_dense_W,
        weight_vec, PMT, mlen, AW[pp], AWC[pp], E,
        GDEC, dec_b, DH, DC, t);
    // K3: softmax + ctx + projections of t-1
    hipLaunchKernelGGL(softmax_ctx_kernel, dim3(32,8), dim3(512), 0, stream,
        E, memory, AW[p], AWC[pp], AWC[p], CTX[p], CTX[pp],
        DH, proj_W, proj_b, gate_W, gate_b, out, aligns, t);
    // K4: decoder LSTM gates (K=2560 = 16 slices of 160)
    hipLaunchKernelGGL((gates_v3<160,1536>), dim3(32,16), dim3(512), 0, stream,
        AH, 1024, CTX[p], 512, DH, 1024,
        dec_Wih, dec_Whh, GDEC);
  }
  hipLaunchKernelGGL(dec_final_kernel, dim3(32), dim3(512), 0, stream,
      GDEC, dec_b, DC, CTX[1], proj_W, proj_b, gate_W, gate_b, out);
}